// Round 7
// baseline (2770.955 us; speedup 1.0000x reference)
//
#include <hip/hip_runtime.h>
#include <hip/hip_bf16.h>

#define BB 8
#define NN 2048
#define DD 128
#define NSTEPS 16
#define DT_F 0.1f
#define TWO_PI_F 6.283185307179586f
#define LDP 136   // B-staging row stride (bf16 elems)
#define CST 520   // C-chunk row stride (bf16 elems)

typedef short short8 __attribute__((ext_vector_type(8)));
typedef float floatx4 __attribute__((ext_vector_type(4)));

// ---------------- K0: split fp32 embeddings into bf16 hi/lo ----------------
__global__ void split_kernel(const float* __restrict__ e,
                             __hip_bfloat16* __restrict__ hi,
                             __hip_bfloat16* __restrict__ lo) {
    int i = blockIdx.x * 256 + threadIdx.x;
    float x = e[i];
    __hip_bfloat16 h = __float2bfloat16(x);
    hi[i] = h;
    lo[i] = __float2bfloat16(x - __bfloat162float(h));
}

// ---- manual per-batch barrier (64 blocks/batch, monotonic counter) --------
__device__ __forceinline__ void batch_barrier(unsigned* cnt, unsigned target) {
    __threadfence();
    __syncthreads();
    if (threadIdx.x == 0) {
        __hip_atomic_fetch_add(cnt, 1u, __ATOMIC_RELEASE, __HIP_MEMORY_SCOPE_AGENT);
        int guard = 0;
        while (__hip_atomic_load(cnt, __ATOMIC_RELAXED, __HIP_MEMORY_SCOPE_AGENT) < target
               && guard < (1 << 24)) {
            __builtin_amdgcn_s_sleep(1);
            ++guard;
        }
    }
    __syncthreads();
    __threadfence();
}

// ---- C held as 32 named uint4 SSA values (NO array -> NO scratch alloca) --
// CREG(r,ch): row r (0..7) of this wave, chunk ch (0..3) = cols ch*512+lane*8..+7
#define CREG(r, ch) c_##r##_##ch
#define DECL_ROW(r) uint4 CREG(r,0), CREG(r,1), CREG(r,2), CREG(r,3);

// readback one row of the LDS C-chunk into CREG(r,ch)
#define RB(r, ch) CREG(r, ch) = *(const uint4*)(Cc + (wave * 8 + (r)) * CST + lane * 8);

// phase-2 accumulate: one packed u32 (2 bf16) into sumc[r]/sums[r]
#define ACC4(r, u, i0) { \
    float f0_ = __uint_as_float((u) << 16); \
    float f1_ = __uint_as_float((u) & 0xffff0000u); \
    sumc[r] = fmaf(f0_, cj[i0],     sumc[r]); \
    sums[r] = fmaf(f0_, sj[i0],     sums[r]); \
    sumc[r] = fmaf(f1_, cj[(i0)+1], sumc[r]); \
    sums[r] = fmaf(f1_, sj[(i0)+1], sums[r]); }

#define ROW_J(r, j) { uint4 u4_ = CREG(r, j); \
    ACC4(r, u4_.x, 0) ACC4(r, u4_.y, 2) ACC4(r, u4_.z, 4) ACC4(r, u4_.w, 6) }

#define DO_J(j) { \
    float4 t0_ = *(const float4*)(tin + (j) * 512 + lane * 8); \
    float4 t1_ = *(const float4*)(tin + (j) * 512 + lane * 8 + 4); \
    float cj[8], sj[8]; \
    __sincosf(t0_.x, &sj[0], &cj[0]); __sincosf(t0_.y, &sj[1], &cj[1]); \
    __sincosf(t0_.z, &sj[2], &cj[2]); __sincosf(t0_.w, &sj[3], &cj[3]); \
    __sincosf(t1_.x, &sj[4], &cj[4]); __sincosf(t1_.y, &sj[5], &cj[5]); \
    __sincosf(t1_.z, &sj[6], &cj[6]); __sincosf(t1_.w, &sj[7], &cj[7]); \
    ROW_J(0, j) ROW_J(1, j) ROW_J(2, j) ROW_J(3, j) \
    ROW_J(4, j) ROW_J(5, j) ROW_J(6, j) ROW_J(7, j) }

#define RED(r) { \
    sumc[r] += __shfl_xor(sumc[r], 32, 64); sums[r] += __shfl_xor(sums[r], 32, 64); \
    sumc[r] += __shfl_xor(sumc[r], 16, 64); sums[r] += __shfl_xor(sums[r], 16, 64); \
    sumc[r] += __shfl_xor(sumc[r],  8, 64); sums[r] += __shfl_xor(sums[r],  8, 64); \
    sumc[r] += __shfl_xor(sumc[r],  4, 64); sums[r] += __shfl_xor(sums[r],  4, 64); \
    sumc[r] += __shfl_xor(sumc[r],  2, 64); sums[r] += __shfl_xor(sums[r],  2, 64); \
    sumc[r] += __shfl_xor(sumc[r],  1, 64); sums[r] += __shfl_xor(sums[r],  1, 64); }

#define WRITE(r) if (lane == (r)) { \
    float sum_ = msn * sumc[r] - mcn * sums[r]; \
    float dth_ = myom + inv * sum_; \
    tout[myrow] = fmodf(myth + DT_F * dth_, TWO_PI_F); }

// phase-1: one 512-col chunk (8 sub-chunks of 64 cols), then readback to CREG
#define DO_CHUNK(ch) { \
    _Pragma("unroll 1") \
    for (int sc = 0; sc < 8; ++sc) { \
        const int m0 = (ch) * 512 + sc * 64; \
        { \
            const __hip_bfloat16* sh = Eb_h + (size_t)m0 * DD; \
            const __hip_bfloat16* sl = Eb_l + (size_t)m0 * DD; \
            _Pragma("unroll") \
            for (int i = 0; i < 4; ++i) { \
                int c_   = tid + 256 * i; \
                int row_ = c_ >> 4; \
                int col_ = (c_ & 15) * 8; \
                *(uint4*)(Bh + row_ * LDP + col_) = *(const uint4*)(sh + row_ * DD + col_); \
                *(uint4*)(Bl + row_ * LDP + col_) = *(const uint4*)(sl + row_ * DD + col_); \
            } \
        } \
        __syncthreads(); \
        _Pragma("unroll") \
        for (int t = 0; t < 2; ++t) { \
            const int ct = ctb + t; \
            floatx4 acc = {0.f, 0.f, 0.f, 0.f}; \
            _Pragma("unroll") \
            for (int kt = 0; kt < 4; ++kt) { \
                const int ko = kt * 32 + quad * 8; \
                short8 bh = *(const short8*)(Bh + (ct * 16 + l16) * LDP + ko); \
                short8 bl = *(const short8*)(Bl + (ct * 16 + l16) * LDP + ko); \
                acc = __builtin_amdgcn_mfma_f32_16x16x32_bf16(ah[kt], bh, acc, 0, 0, 0); \
                acc = __builtin_amdgcn_mfma_f32_16x16x32_bf16(ah[kt], bl, acc, 0, 0, 0); \
                acc = __builtin_amdgcn_mfma_f32_16x16x32_bf16(al[kt], bh, acc, 0, 0, 0); \
            } \
            float tm = __bfloat162float(Bh[(ct * 16 + l16) * LDP]) + \
                       __bfloat162float(Bl[(ct * 16 + l16) * LDP]); \
            _Pragma("unroll") \
            for (int i = 0; i < 4; ++i) { \
                float arg = fmaxf(fmaf(tn2[i], tm, -acc[i]), 1.0f + 1e-7f); \
                float s_  = sqrtf(fmaf(arg, arg, -1.0f)); \
                float cp  = __builtin_amdgcn_rcpf(arg + s_); \
                int lrow  = art * 16 + quad * 4 + i; \
                int ccol  = sc * 64 + ct * 16 + l16; \
                Cc[lrow * CST + ccol] = __float2bfloat16(fminf(cp, 1.0f)); \
            } \
        } \
        __syncthreads(); \
    } \
    RB(0, ch) RB(1, ch) RB(2, ch) RB(3, ch) RB(4, ch) RB(5, ch) RB(6, ch) RB(7, ch) }

// ---------------- fused: build C in registers, run all 16 steps ------------
__launch_bounds__(256, 2)
__global__ void fused_kernel(const __hip_bfloat16* __restrict__ Ehi,
                             const __hip_bfloat16* __restrict__ Elo,
                             const float* __restrict__ theta0,
                             const float* __restrict__ omega,
                             float* __restrict__ tA,
                             float* __restrict__ tB,
                             float* __restrict__ out,
                             unsigned* __restrict__ barrier_cnt) {
    __shared__ __align__(16) char smem[68096];
    __hip_bfloat16* Bh = (__hip_bfloat16*)smem;            // 17408 B
    __hip_bfloat16* Bl = (__hip_bfloat16*)(smem + 17408);  // 17408 B
    __hip_bfloat16* Cc = (__hip_bfloat16*)(smem + 34816);  // 33280 B

    const int tid  = threadIdx.x;
    const int lane = tid & 63;
    const int wave = tid >> 6;
    const int l16  = lane & 15;
    const int quad = lane >> 4;

    const int b    = blockIdx.x >> 6;      // batch
    const int rg   = blockIdx.x & 63;
    const int row0 = rg * 32;              // row base within batch
    const int art  = wave & 1;             // phase-1 row-tile (16 rows)
    const int ctb  = (wave >> 1) * 2;      // phase-1 col-tile base {0,2}

    const __hip_bfloat16* Eb_h = Ehi + (size_t)b * NN * DD;
    const __hip_bfloat16* Eb_l = Elo + (size_t)b * NN * DD;

    short8 ah[4], al[4];
    {
        const __hip_bfloat16* ph = Eb_h + (size_t)(row0 + art * 16 + l16) * DD + quad * 8;
        const __hip_bfloat16* pl = Eb_l + (size_t)(row0 + art * 16 + l16) * DD + quad * 8;
        #pragma unroll
        for (int kt = 0; kt < 4; ++kt) {
            ah[kt] = *(const short8*)(ph + kt * 32);
            al[kt] = *(const short8*)(pl + kt * 32);
        }
    }
    float tn2[4];
    #pragma unroll
    for (int i = 0; i < 4; ++i) {
        int rr = row0 + art * 16 + quad * 4 + i;
        tn2[i] = 2.0f * (__bfloat162float(Eb_h[(size_t)rr * DD]) +
                         __bfloat162float(Eb_l[(size_t)rr * DD]));
    }

    DECL_ROW(0) DECL_ROW(1) DECL_ROW(2) DECL_ROW(3)
    DECL_ROW(4) DECL_ROW(5) DECL_ROW(6) DECL_ROW(7)

    // ---- phase 1 ----
    DO_CHUNK(0)
    DO_CHUNK(1)
    DO_CHUNK(2)
    DO_CHUNK(3)

    // ---- phase 2: 16 steps, C in named registers ----
    const float inv = 1.0f / NN;
    unsigned* cnt = barrier_cnt + b * 32;
    #pragma unroll 1
    for (int s = 0; s < NSTEPS; ++s) {
        const float* tin = (s == 0) ? (theta0 + b * NN)
                                    : (((s & 1) ? tA : tB) + b * NN);
        float* tout = (s == NSTEPS - 1) ? (out + b * NN)
                                        : (((s & 1) ? tB : tA) + b * NN);

        float sumc[8] = {0, 0, 0, 0, 0, 0, 0, 0};
        float sums[8] = {0, 0, 0, 0, 0, 0, 0, 0};

        DO_J(0) DO_J(1) DO_J(2) DO_J(3)

        RED(0) RED(1) RED(2) RED(3) RED(4) RED(5) RED(6) RED(7)

        int myrow  = row0 + wave * 8 + (lane & 7);
        float myth = tin[myrow];
        float msn, mcn;
        __sincosf(myth, &msn, &mcn);
        float myom = omega[myrow];
        WRITE(0) WRITE(1) WRITE(2) WRITE(3)
        WRITE(4) WRITE(5) WRITE(6) WRITE(7)

        if (s < NSTEPS - 1) batch_barrier(cnt, 64u * (unsigned)(s + 1));
    }
}

// ---------------- launch ----------------------------------------------------
extern "C" void kernel_launch(void* const* d_in, const int* in_sizes, int n_in,
                              void* d_out, int out_size, void* d_ws, size_t ws_size,
                              hipStream_t stream) {
    const float* theta0 = (const float*)d_in[0];
    const float* emb    = (const float*)d_in[1];
    const float* omega  = (const float*)d_in[2];
    float* out = (float*)d_out;

    char* ws = (char*)d_ws;
    __hip_bfloat16* Ehi = (__hip_bfloat16*)ws;                    // 4 MiB
    __hip_bfloat16* Elo = (__hip_bfloat16*)(ws + (4 << 20));      // 4 MiB
    float* tA     = (float*)(ws + (8 << 20));                     // 64 KiB
    float* tB     = (float*)(ws + (8 << 20) + 65536);             // 64 KiB
    unsigned* cnt = (unsigned*)(ws + (8 << 20) + 131072);         // 8 x 128 B

    hipMemsetAsync(cnt, 0, BB * 32 * sizeof(unsigned), stream);

    split_kernel<<<(BB * NN * DD) / 256, 256, 0, stream>>>(emb, Ehi, Elo);

    fused_kernel<<<dim3(512), dim3(256), 0, stream>>>(Ehi, Elo, theta0, omega,
                                                      tA, tB, out, cnt);
}

// Round 8
// 1215.469 us; speedup vs baseline: 2.2797x; 2.2797x over previous
//
#include <hip/hip_runtime.h>
#include <hip/hip_bf16.h>

#define BB 8
#define NN 2048
#define DD 128
#define NSTEPS 16
#define DT_F 0.1f
#define TWO_PI_F 6.283185307179586f
#define LDP 136   // B-staging row stride (bf16 elems)
#define CST 520   // C-chunk row stride (bf16 elems)

typedef short short8 __attribute__((ext_vector_type(8)));
typedef float floatx4 __attribute__((ext_vector_type(4)));

// ---------------- K0: split fp32 embeddings into bf16 hi/lo ----------------
__global__ void split_kernel(const float* __restrict__ e,
                             __hip_bfloat16* __restrict__ hi,
                             __hip_bfloat16* __restrict__ lo) {
    int i = blockIdx.x * 256 + threadIdx.x;
    float x = e[i];
    __hip_bfloat16 h = __float2bfloat16(x);
    hi[i] = h;
    lo[i] = __float2bfloat16(x - __bfloat162float(h));
}

// ---- manual per-batch barrier (64 blocks/batch, monotonic counter) --------
__device__ __forceinline__ void batch_barrier(unsigned* cnt, unsigned target) {
    __threadfence();
    __syncthreads();
    if (threadIdx.x == 0) {
        __hip_atomic_fetch_add(cnt, 1u, __ATOMIC_RELEASE, __HIP_MEMORY_SCOPE_AGENT);
        int guard = 0;
        while (__hip_atomic_load(cnt, __ATOMIC_RELAXED, __HIP_MEMORY_SCOPE_AGENT) < target
               && guard < (1 << 24)) {
            __builtin_amdgcn_s_sleep(1);
            ++guard;
        }
    }
    __syncthreads();
    __threadfence();
}

// ---- C pinned in AGPRs: 128 named values, def by v_accvgpr_write ("=a"),
//      use by v_accvgpr_read ("a"). The accum half of the unified RF holds C;
//      the arch half keeps the working set. No scratch.
#define AC(r, ch, k) a_##r##_##ch##_##k
#define DECL_CH(r, ch) unsigned AC(r,ch,0), AC(r,ch,1), AC(r,ch,2), AC(r,ch,3);
#define DECL_ROW(r) DECL_CH(r,0) DECL_CH(r,1) DECL_CH(r,2) DECL_CH(r,3)

#define AW(dst, src) __asm__("v_accvgpr_write_b32 %0, %1" : "=a"(dst) : "v"(src));
#define AR(dst, src) __asm__("v_accvgpr_read_b32 %0, %1"  : "=v"(dst) : "a"(src));

// readback one row-chunk of the LDS C-tile into AGPRs
#define RB(r, ch) { \
    uint4 v_ = *(const uint4*)(Cc + (wave * 8 + (r)) * CST + lane * 8); \
    AW(AC(r,ch,0), v_.x) AW(AC(r,ch,1), v_.y) AW(AC(r,ch,2), v_.z) AW(AC(r,ch,3), v_.w) }

// phase-2 accumulate: one packed u32 (2 bf16) into sumc[r]/sums[r]
#define ACC4(r, u, i0) { \
    float f0_ = __uint_as_float((u) << 16); \
    float f1_ = __uint_as_float((u) & 0xffff0000u); \
    sumc[r] = fmaf(f0_, cj[i0],     sumc[r]); \
    sums[r] = fmaf(f0_, sj[i0],     sums[r]); \
    sumc[r] = fmaf(f1_, cj[(i0)+1], sumc[r]); \
    sums[r] = fmaf(f1_, sj[(i0)+1], sums[r]); }

#define ROW_J(r, j) { unsigned u0_, u1_, u2_, u3_; \
    AR(u0_, AC(r,j,0)) AR(u1_, AC(r,j,1)) AR(u2_, AC(r,j,2)) AR(u3_, AC(r,j,3)) \
    ACC4(r, u0_, 0) ACC4(r, u1_, 2) ACC4(r, u2_, 4) ACC4(r, u3_, 6) }

#define DO_J(j) { \
    float4 t0_ = *(const float4*)(tin + (j) * 512 + lane * 8); \
    float4 t1_ = *(const float4*)(tin + (j) * 512 + lane * 8 + 4); \
    float cj[8], sj[8]; \
    __sincosf(t0_.x, &sj[0], &cj[0]); __sincosf(t0_.y, &sj[1], &cj[1]); \
    __sincosf(t0_.z, &sj[2], &cj[2]); __sincosf(t0_.w, &sj[3], &cj[3]); \
    __sincosf(t1_.x, &sj[4], &cj[4]); __sincosf(t1_.y, &sj[5], &cj[5]); \
    __sincosf(t1_.z, &sj[6], &cj[6]); __sincosf(t1_.w, &sj[7], &cj[7]); \
    ROW_J(0, j) ROW_J(1, j) ROW_J(2, j) ROW_J(3, j) \
    ROW_J(4, j) ROW_J(5, j) ROW_J(6, j) ROW_J(7, j) }

#define RED(r) { \
    sumc[r] += __shfl_xor(sumc[r], 32, 64); sums[r] += __shfl_xor(sums[r], 32, 64); \
    sumc[r] += __shfl_xor(sumc[r], 16, 64); sums[r] += __shfl_xor(sums[r], 16, 64); \
    sumc[r] += __shfl_xor(sumc[r],  8, 64); sums[r] += __shfl_xor(sums[r],  8, 64); \
    sumc[r] += __shfl_xor(sumc[r],  4, 64); sums[r] += __shfl_xor(sums[r],  4, 64); \
    sumc[r] += __shfl_xor(sumc[r],  2, 64); sums[r] += __shfl_xor(sums[r],  2, 64); \
    sumc[r] += __shfl_xor(sumc[r],  1, 64); sums[r] += __shfl_xor(sums[r],  1, 64); }

#define WRITE(r) if (lane == (r)) { \
    float sum_ = msn * sumc[r] - mcn * sums[r]; \
    float dth_ = myom + inv * sum_; \
    tout[myrow] = fmodf(myth + DT_F * dth_, TWO_PI_F); }

// phase-1: one 512-col chunk (8 sub-chunks of 64 cols), then readback to AGPRs
#define DO_CHUNK(ch) { \
    _Pragma("unroll 1") \
    for (int sc = 0; sc < 8; ++sc) { \
        const int m0 = (ch) * 512 + sc * 64; \
        { \
            const __hip_bfloat16* sh = Eb_h + (size_t)m0 * DD; \
            const __hip_bfloat16* sl = Eb_l + (size_t)m0 * DD; \
            _Pragma("unroll") \
            for (int i = 0; i < 4; ++i) { \
                int c_   = tid + 256 * i; \
                int row_ = c_ >> 4; \
                int col_ = (c_ & 15) * 8; \
                *(uint4*)(Bh + row_ * LDP + col_) = *(const uint4*)(sh + row_ * DD + col_); \
                *(uint4*)(Bl + row_ * LDP + col_) = *(const uint4*)(sl + row_ * DD + col_); \
            } \
        } \
        __syncthreads(); \
        _Pragma("unroll") \
        for (int t = 0; t < 2; ++t) { \
            const int ct = ctb + t; \
            floatx4 acc = {0.f, 0.f, 0.f, 0.f}; \
            _Pragma("unroll") \
            for (int kt = 0; kt < 4; ++kt) { \
                const int ko = kt * 32 + quad * 8; \
                short8 bh = *(const short8*)(Bh + (ct * 16 + l16) * LDP + ko); \
                short8 bl = *(const short8*)(Bl + (ct * 16 + l16) * LDP + ko); \
                acc = __builtin_amdgcn_mfma_f32_16x16x32_bf16(ah[kt], bh, acc, 0, 0, 0); \
                acc = __builtin_amdgcn_mfma_f32_16x16x32_bf16(ah[kt], bl, acc, 0, 0, 0); \
                acc = __builtin_amdgcn_mfma_f32_16x16x32_bf16(al[kt], bh, acc, 0, 0, 0); \
            } \
            float tm = __bfloat162float(Bh[(ct * 16 + l16) * LDP]) + \
                       __bfloat162float(Bl[(ct * 16 + l16) * LDP]); \
            _Pragma("unroll") \
            for (int i = 0; i < 4; ++i) { \
                float arg = fmaxf(fmaf(tn2[i], tm, -acc[i]), 1.0f + 1e-7f); \
                float s_  = sqrtf(fmaf(arg, arg, -1.0f)); \
                float cp  = __builtin_amdgcn_rcpf(arg + s_); \
                int lrow  = art * 16 + quad * 4 + i; \
                int ccol  = sc * 64 + ct * 16 + l16; \
                Cc[lrow * CST + ccol] = __float2bfloat16(fminf(cp, 1.0f)); \
            } \
        } \
        __syncthreads(); \
    } \
    RB(0, ch) RB(1, ch) RB(2, ch) RB(3, ch) RB(4, ch) RB(5, ch) RB(6, ch) RB(7, ch) }

// ---------------- fused: build C in AGPRs, run all 16 steps ----------------
__attribute__((amdgpu_waves_per_eu(2, 2)))
__launch_bounds__(256, 2)
__global__ void fused_kernel(const __hip_bfloat16* __restrict__ Ehi,
                             const __hip_bfloat16* __restrict__ Elo,
                             const float* __restrict__ theta0,
                             const float* __restrict__ omega,
                             float* __restrict__ tA,
                             float* __restrict__ tB,
                             float* __restrict__ out,
                             unsigned* __restrict__ barrier_cnt) {
    __shared__ __align__(16) char smem[68096];
    __hip_bfloat16* Bh = (__hip_bfloat16*)smem;            // 17408 B
    __hip_bfloat16* Bl = (__hip_bfloat16*)(smem + 17408);  // 17408 B
    __hip_bfloat16* Cc = (__hip_bfloat16*)(smem + 34816);  // 33280 B

    const int tid  = threadIdx.x;
    const int lane = tid & 63;
    const int wave = tid >> 6;
    const int l16  = lane & 15;
    const int quad = lane >> 4;

    const int b    = blockIdx.x >> 6;      // batch
    const int rg   = blockIdx.x & 63;
    const int row0 = rg * 32;              // row base within batch
    const int art  = wave & 1;             // phase-1 row-tile (16 rows)
    const int ctb  = (wave >> 1) * 2;      // phase-1 col-tile base {0,2}

    const __hip_bfloat16* Eb_h = Ehi + (size_t)b * NN * DD;
    const __hip_bfloat16* Eb_l = Elo + (size_t)b * NN * DD;

    short8 ah[4], al[4];
    {
        const __hip_bfloat16* ph = Eb_h + (size_t)(row0 + art * 16 + l16) * DD + quad * 8;
        const __hip_bfloat16* pl = Eb_l + (size_t)(row0 + art * 16 + l16) * DD + quad * 8;
        #pragma unroll
        for (int kt = 0; kt < 4; ++kt) {
            ah[kt] = *(const short8*)(ph + kt * 32);
            al[kt] = *(const short8*)(pl + kt * 32);
        }
    }
    float tn2[4];
    #pragma unroll
    for (int i = 0; i < 4; ++i) {
        int rr = row0 + art * 16 + quad * 4 + i;
        tn2[i] = 2.0f * (__bfloat162float(Eb_h[(size_t)rr * DD]) +
                         __bfloat162float(Eb_l[(size_t)rr * DD]));
    }

    DECL_ROW(0) DECL_ROW(1) DECL_ROW(2) DECL_ROW(3)
    DECL_ROW(4) DECL_ROW(5) DECL_ROW(6) DECL_ROW(7)

    // ---- phase 1 ----
    DO_CHUNK(0)
    DO_CHUNK(1)
    DO_CHUNK(2)
    DO_CHUNK(3)

    // ---- phase 2: 16 steps, C in AGPRs ----
    const float inv = 1.0f / NN;
    unsigned* cnt = barrier_cnt + b * 32;
    #pragma unroll 1
    for (int s = 0; s < NSTEPS; ++s) {
        const float* tin = (s == 0) ? (theta0 + b * NN)
                                    : (((s & 1) ? tA : tB) + b * NN);
        float* tout = (s == NSTEPS - 1) ? (out + b * NN)
                                        : (((s & 1) ? tB : tA) + b * NN);

        float sumc[8] = {0, 0, 0, 0, 0, 0, 0, 0};
        float sums[8] = {0, 0, 0, 0, 0, 0, 0, 0};

        DO_J(0) DO_J(1) DO_J(2) DO_J(3)

        RED(0) RED(1) RED(2) RED(3) RED(4) RED(5) RED(6) RED(7)

        int myrow  = row0 + wave * 8 + (lane & 7);
        float myth = tin[myrow];
        float msn, mcn;
        __sincosf(myth, &msn, &mcn);
        float myom = omega[myrow];
        WRITE(0) WRITE(1) WRITE(2) WRITE(3)
        WRITE(4) WRITE(5) WRITE(6) WRITE(7)

        if (s < NSTEPS - 1) batch_barrier(cnt, 64u * (unsigned)(s + 1));
    }
}

// ---------------- launch ----------------------------------------------------
extern "C" void kernel_launch(void* const* d_in, const int* in_sizes, int n_in,
                              void* d_out, int out_size, void* d_ws, size_t ws_size,
                              hipStream_t stream) {
    const float* theta0 = (const float*)d_in[0];
    const float* emb    = (const float*)d_in[1];
    const float* omega  = (const float*)d_in[2];
    float* out = (float*)d_out;

    char* ws = (char*)d_ws;
    __hip_bfloat16* Ehi = (__hip_bfloat16*)ws;                    // 4 MiB
    __hip_bfloat16* Elo = (__hip_bfloat16*)(ws + (4 << 20));      // 4 MiB
    float* tA     = (float*)(ws + (8 << 20));                     // 64 KiB
    float* tB     = (float*)(ws + (8 << 20) + 65536);             // 64 KiB
    unsigned* cnt = (unsigned*)(ws + (8 << 20) + 131072);         // 8 x 128 B

    hipMemsetAsync(cnt, 0, BB * 32 * sizeof(unsigned), stream);

    split_kernel<<<(BB * NN * DD) / 256, 256, 0, stream>>>(emb, Ehi, Elo);

    fused_kernel<<<dim3(512), dim3(256), 0, stream>>>(Ehi, Elo, theta0, omega,
                                                      tA, tB, out, cnt);
}